// Round 1
// baseline (409.921 us; speedup 1.0000x reference)
//
#include <hip/hip_runtime.h>
#include <hip/hip_bf16.h>

// OneHotPooling: out[o,f] = mean_{e: seg[e]==o} exp(-softplus(raw[f]) * (times_out[pred[e,f]] - times_in[e]))
//
// Strategy: build inverted index (histogram -> exclusive scan -> scatter), then
// one wave64 per output row: lane l handles filters 2l,2l+1 (int2/float2),
// pred-row loads coalesced 512B, times_out gathers hit L2 (1MB table),
// output written exactly once (no atomics on the 128MB output).

#define LOG2E 1.4426950408889634f

__global__ void k_init(int* __restrict__ counts, int* __restrict__ cursor,
                       float* __restrict__ rates, const float* __restrict__ raw,
                       int e_out, int f) {
  int i = blockIdx.x * blockDim.x + threadIdx.x;
  if (i < e_out) { counts[i] = 0; cursor[i] = 0; }
  if (i < f) {
    float x = raw[i];
    float sp = (x > 20.0f) ? x : log1pf(expf(x));   // softplus
    rates[i] = -sp * LOG2E;                          // so weight = exp2(rates[f]*dt)
  }
}

__global__ void k_hist(const int* __restrict__ seg, int* __restrict__ counts, int e_in) {
  int i = blockIdx.x * blockDim.x + threadIdx.x;
  if (i < e_in) atomicAdd(&counts[seg[i]], 1);
}

// Each block: exclusive scan of 256 counts into cursor; block total -> bsum[bid].
__global__ void k_scan1(const int* __restrict__ counts, int* __restrict__ cursor,
                        int* __restrict__ bsum, int e_out) {
  __shared__ int sh[256];
  int gid = blockIdx.x * 256 + threadIdx.x;
  int v = (gid < e_out) ? counts[gid] : 0;
  sh[threadIdx.x] = v;
  __syncthreads();
  for (int off = 1; off < 256; off <<= 1) {
    int t = (threadIdx.x >= off) ? sh[threadIdx.x - off] : 0;
    __syncthreads();
    sh[threadIdx.x] += t;
    __syncthreads();
  }
  if (gid < e_out) cursor[gid] = sh[threadIdx.x] - v;  // exclusive (local)
  if (threadIdx.x == 255) bsum[blockIdx.x] = sh[255];
}

// Single block: in-place exclusive scan of up to 1024 block sums.
__global__ void k_scan2(int* __restrict__ bsum, int nblocks) {
  __shared__ int sh[1024];
  int v = (threadIdx.x < nblocks) ? bsum[threadIdx.x] : 0;
  sh[threadIdx.x] = v;
  __syncthreads();
  for (int off = 1; off < 1024; off <<= 1) {
    int t = (threadIdx.x >= off) ? sh[threadIdx.x - off] : 0;
    __syncthreads();
    sh[threadIdx.x] += t;
    __syncthreads();
  }
  if (threadIdx.x < nblocks) bsum[threadIdx.x] = sh[threadIdx.x] - v;
}

__global__ void k_scatter(const int* __restrict__ seg, int* __restrict__ cursor,
                          const int* __restrict__ bsum, int* __restrict__ list, int e_in) {
  int i = blockIdx.x * blockDim.x + threadIdx.x;
  if (i < e_in) {
    int s = seg[i];
    int pos = atomicAdd(&cursor[s], 1);        // local rank within row
    list[bsum[s >> 8] + pos] = i;              // absolute position
  }
}

// One wave64 per output row. Lane l: filters 2l, 2l+1.
__global__ __launch_bounds__(256) void k_main(
    const float* __restrict__ times_in,
    const float* __restrict__ times_out,
    const float* __restrict__ rates,
    const int* __restrict__ counts,
    const int* __restrict__ cursor,   // after scatter: local end = local start + count
    const int* __restrict__ bsum,
    const int* __restrict__ list,
    const int2* __restrict__ preds,   // [E_IN][64] as int2
    float2* __restrict__ out,         // [E_OUT][64] as float2
    int e_out) {
  int wave = (int)((blockIdx.x * (unsigned)blockDim.x + threadIdx.x) >> 6);
  int lane = threadIdx.x & 63;
  if (wave >= e_out) return;

  int cnt = counts[wave];
  int end = cursor[wave] + bsum[wave >> 8];
  int start = end - cnt;

  float rn0 = rates[2 * lane];
  float rn1 = rates[2 * lane + 1];
  float a0 = 0.0f, a1 = 0.0f;

  for (int i = start; i < end; ++i) {
    int e = __builtin_amdgcn_readfirstlane(list[i]);   // wave-uniform
    float tin = times_in[e];
    int2 p = preds[(size_t)e * 64 + lane];             // coalesced 512B row
    float t0 = times_out[p.x];                         // L2-resident gather
    float t1 = times_out[p.y];
    a0 += exp2f(rn0 * (t0 - tin));
    a1 += exp2f(rn1 * (t1 - tin));
  }

  float inv = 1.0f / (float)(cnt > 0 ? cnt : 1);
  out[(size_t)wave * 64 + lane] = make_float2(a0 * inv, a1 * inv);
}

static inline size_t align_up(size_t x, size_t a) { return (x + a - 1) & ~(a - 1); }

extern "C" void kernel_launch(void* const* d_in, const int* in_sizes, int n_in,
                              void* d_out, int out_size, void* d_ws, size_t ws_size,
                              hipStream_t stream) {
  const float* times_in  = (const float*)d_in[0];
  const float* times_out = (const float*)d_in[1];
  const float* raw       = (const float*)d_in[2];
  const int*   seg       = (const int*)d_in[3];
  const int*   preds     = (const int*)d_in[4];

  const int e_in  = in_sizes[0];
  const int e_out = in_sizes[1];
  const int f     = in_sizes[2];       // layout below assumes f == 128
  const int nblk  = (e_out + 255) / 256;

  // Workspace layout
  char* ws = (char*)d_ws;
  size_t off = 0;
  int* counts = (int*)(ws + off); off = align_up(off + (size_t)e_out * 4, 256);
  int* cursor = (int*)(ws + off); off = align_up(off + (size_t)e_out * 4, 256);
  int* bsum   = (int*)(ws + off); off = align_up(off + (size_t)nblk * 4, 256);
  float* rates= (float*)(ws + off); off = align_up(off + (size_t)f * 4, 256);
  int* list   = (int*)(ws + off); off = align_up(off + (size_t)e_in * 4, 256);
  (void)ws_size;

  int tb = 256;
  k_init<<<dim3((e_out + tb - 1) / tb), dim3(tb), 0, stream>>>(counts, cursor, rates, raw, e_out, f);
  k_hist<<<dim3((e_in + tb - 1) / tb), dim3(tb), 0, stream>>>(seg, counts, e_in);
  k_scan1<<<dim3(nblk), dim3(256), 0, stream>>>(counts, cursor, bsum, e_out);
  k_scan2<<<dim3(1), dim3(1024), 0, stream>>>(bsum, nblk);
  k_scatter<<<dim3((e_in + tb - 1) / tb), dim3(tb), 0, stream>>>(seg, cursor, bsum, list, e_in);

  int waves = e_out;                              // one wave per output row
  int blocks = (waves * 64 + tb - 1) / tb;        // 4 waves per block
  k_main<<<dim3(blocks), dim3(tb), 0, stream>>>(
      times_in, times_out, rates, counts, cursor, bsum, list,
      (const int2*)preds, (float2*)d_out, e_out);
}

// Round 2
// 395.215 us; speedup vs baseline: 1.0372x; 1.0372x over previous
//
#include <hip/hip_runtime.h>
#include <hip/hip_bf16.h>

// OneHotPooling: out[o,f] = mean_{e: seg[e]==o} exp(-softplus(raw[f]) * (times_out[pred[e,f]] - times_in[e]))
//
// Strategy: inverted index (hist -> scan -> fix -> scatter), then TWO waves per
// output row (lane = 1 filter). Pair-unrolled event loop gives two independent
// load chains; preds streamed with nt hint; times_out gathers stay L2-hot.

#define LOG2E 1.4426950408889634f

__global__ void k_init(int* __restrict__ counts, float* __restrict__ rates,
                       const float* __restrict__ raw, int e_out, int f) {
  int i = blockIdx.x * blockDim.x + threadIdx.x;
  if (i < e_out) counts[i] = 0;
  if (i < f) {
    float x = raw[i];
    float sp = (x > 20.0f) ? x : log1pf(expf(x));   // softplus
    rates[i] = -sp * LOG2E;                          // weight = exp2(rates[f]*dt)
  }
}

__global__ void k_hist(const int* __restrict__ seg, int* __restrict__ counts, int e_in) {
  int i = blockIdx.x * blockDim.x + threadIdx.x;
  if (i < e_in) atomicAdd(&counts[seg[i]], 1);
}

// Each block: exclusive scan of 256 counts into cursor (local); block total -> bsum[bid].
__global__ void k_scan1(const int* __restrict__ counts, int* __restrict__ cursor,
                        int* __restrict__ bsum, int e_out) {
  __shared__ int sh[256];
  int gid = blockIdx.x * 256 + threadIdx.x;
  int v = (gid < e_out) ? counts[gid] : 0;
  sh[threadIdx.x] = v;
  __syncthreads();
  for (int off = 1; off < 256; off <<= 1) {
    int t = (threadIdx.x >= off) ? sh[threadIdx.x - off] : 0;
    __syncthreads();
    sh[threadIdx.x] += t;
    __syncthreads();
  }
  if (gid < e_out) cursor[gid] = sh[threadIdx.x] - v;  // exclusive (local)
  if (threadIdx.x == 255) bsum[blockIdx.x] = sh[255];
}

// Single block: in-place exclusive scan of up to 1024 block sums.
__global__ void k_scan2(int* __restrict__ bsum, int nblocks) {
  __shared__ int sh[1024];
  int v = (threadIdx.x < nblocks) ? bsum[threadIdx.x] : 0;
  sh[threadIdx.x] = v;
  __syncthreads();
  for (int off = 1; off < 1024; off <<= 1) {
    int t = (threadIdx.x >= off) ? sh[threadIdx.x - off] : 0;
    __syncthreads();
    sh[threadIdx.x] += t;
    __syncthreads();
  }
  if (threadIdx.x < nblocks) bsum[threadIdx.x] = sh[threadIdx.x] - v;
}

// cursor becomes the GLOBAL start of each row.
__global__ void k_fix(int* __restrict__ cursor, const int* __restrict__ bsum, int e_out) {
  int i = blockIdx.x * blockDim.x + threadIdx.x;
  if (i < e_out) cursor[i] += bsum[i >> 8];
}

// After scatter, cursor[s] = global END of row s.
__global__ void k_scatter(const int* __restrict__ seg, int* __restrict__ cursor,
                          int* __restrict__ list, int e_in) {
  int i = blockIdx.x * blockDim.x + threadIdx.x;
  if (i < e_in) {
    int pos = atomicAdd(&cursor[seg[i]], 1);
    list[pos] = i;
  }
}

// TWO waves per output row; wave half h covers filters [h*64, h*64+64), 1/lane.
__global__ __launch_bounds__(256) void k_main(
    const float* __restrict__ times_in,
    const float* __restrict__ times_out,
    const float* __restrict__ rates,
    const int* __restrict__ counts,
    const int* __restrict__ cursor,   // global end per row
    const int* __restrict__ list,
    const int* __restrict__ preds,    // [E_IN][128]
    float* __restrict__ out,          // [E_OUT][128]
    int e_out) {
  int gwave = (int)((blockIdx.x * (unsigned)blockDim.x + threadIdx.x) >> 6);
  int row = gwave >> 1;
  int half = gwave & 1;
  int lane = threadIdx.x & 63;
  if (row >= e_out) return;

  int fcol = half * 64 + lane;
  int cnt = counts[row];
  int end = cursor[row];
  int start = end - cnt;

  float rn = rates[fcol];
  float acc = 0.0f;

  int i = start;
  // pair-unrolled: two independent chains per iteration
  for (; i + 2 <= end; i += 2) {
    int e0 = __builtin_amdgcn_readfirstlane(list[i]);
    int e1 = __builtin_amdgcn_readfirstlane(list[i + 1]);
    float tin0 = times_in[e0];
    float tin1 = times_in[e1];
    int p0 = __builtin_nontemporal_load(&preds[(size_t)e0 * 128 + fcol]);
    int p1 = __builtin_nontemporal_load(&preds[(size_t)e1 * 128 + fcol]);
    float to0 = times_out[p0];
    float to1 = times_out[p1];
    acc += exp2f(rn * (to0 - tin0));
    acc += exp2f(rn * (to1 - tin1));
  }
  if (i < end) {
    int e0 = __builtin_amdgcn_readfirstlane(list[i]);
    float tin0 = times_in[e0];
    int p0 = __builtin_nontemporal_load(&preds[(size_t)e0 * 128 + fcol]);
    float to0 = times_out[p0];
    acc += exp2f(rn * (to0 - tin0));
  }

  float inv = 1.0f / (float)(cnt > 0 ? cnt : 1);
  __builtin_nontemporal_store(acc * inv, &out[(size_t)row * 128 + fcol]);
}

static inline size_t align_up(size_t x, size_t a) { return (x + a - 1) & ~(a - 1); }

extern "C" void kernel_launch(void* const* d_in, const int* in_sizes, int n_in,
                              void* d_out, int out_size, void* d_ws, size_t ws_size,
                              hipStream_t stream) {
  const float* times_in  = (const float*)d_in[0];
  const float* times_out = (const float*)d_in[1];
  const float* raw       = (const float*)d_in[2];
  const int*   seg       = (const int*)d_in[3];
  const int*   preds     = (const int*)d_in[4];

  const int e_in  = in_sizes[0];
  const int e_out = in_sizes[1];
  const int f     = in_sizes[2];       // layout assumes f == 128
  const int nblk  = (e_out + 255) / 256;

  // Workspace layout (~4 MB)
  char* ws = (char*)d_ws;
  size_t off = 0;
  int* counts = (int*)(ws + off); off = align_up(off + (size_t)e_out * 4, 256);
  int* cursor = (int*)(ws + off); off = align_up(off + (size_t)e_out * 4, 256);
  int* bsum   = (int*)(ws + off); off = align_up(off + (size_t)nblk * 4, 256);
  float* rates= (float*)(ws + off); off = align_up(off + (size_t)f * 4, 256);
  int* list   = (int*)(ws + off); off = align_up(off + (size_t)e_in * 4, 256);
  (void)ws_size;

  int tb = 256;
  k_init<<<dim3((e_out + tb - 1) / tb), dim3(tb), 0, stream>>>(counts, rates, raw, e_out, f);
  k_hist<<<dim3((e_in + tb - 1) / tb), dim3(tb), 0, stream>>>(seg, counts, e_in);
  k_scan1<<<dim3(nblk), dim3(256), 0, stream>>>(counts, cursor, bsum, e_out);
  k_scan2<<<dim3(1), dim3(1024), 0, stream>>>(bsum, nblk);
  k_fix<<<dim3((e_out + tb - 1) / tb), dim3(tb), 0, stream>>>(cursor, bsum, e_out);
  k_scatter<<<dim3((e_in + tb - 1) / tb), dim3(tb), 0, stream>>>(seg, cursor, list, e_in);

  long long waves = (long long)e_out * 2;          // two waves per row
  int blocks = (int)((waves * 64 + tb - 1) / tb);  // 4 waves per block
  k_main<<<dim3(blocks), dim3(tb), 0, stream>>>(
      times_in, times_out, rates, counts, cursor, list, preds, (float*)d_out, e_out);
}